// Round 17
// baseline (444.566 us; speedup 1.0000x reference)
//
#include <hip/hip_runtime.h>

typedef __attribute__((ext_vector_type(8))) __bf16 bf16x8;
typedef __attribute__((ext_vector_type(8))) unsigned short ushort8;
typedef __attribute__((ext_vector_type(4))) float f32x4;
typedef __attribute__((ext_vector_type(2))) unsigned long long u64x2;

#define DEVINL __device__ __forceinline__
#define RLX __ATOMIC_RELAXED
#define AGT __HIP_MEMORY_SCOPE_AGENT

constexpr int B_C    = 512;
constexpr int DIMS_C = 784;
constexpr int T_C    = 55;      // K1*N time steps
constexpr int I0_C   = 789;     // DIMS + N
constexpr int KP_C   = 800;     // padded K for gemm1 (25 * 32)
constexpr int H_C    = 512;
constexpr int G4_C   = 2048;    // 4*H
constexpr int M1_C   = 28160;   // T_C * B_C, rows ordered r = t*512 + b

// ---- workspace layout (bytes, all 256-aligned) ----
constexpr size_t OFF_A    = 0;                                   // bf16 [M1][KP]
constexpr size_t SZ_A     = (size_t)M1_C * KP_C * 2;
constexpr size_t OFF_W1T  = OFF_A + SZ_A;                        // bf16 [2048][KP]
constexpr size_t SZ_W1T   = (size_t)G4_C * KP_C * 2;
constexpr size_t OFF_U1T  = OFF_W1T + SZ_W1T;                    // bf16 [2048][512]
constexpr size_t SZ_U1T   = (size_t)G4_C * H_C * 2;
constexpr size_t OFF_XW1  = OFF_U1T + SZ_U1T;                    // fp16 [M1][2048]
constexpr size_t SZ_XW1   = (size_t)M1_C * G4_C * 2;
constexpr size_t OFF_H    = OFF_XW1 + SZ_XW1;                    // bf16 [2][512][512]
constexpr size_t SZ_H     = (size_t)2 * B_C * H_C * 2;
constexpr size_t OFF_XMID = OFF_H + SZ_H;                        // f32 [M1][512]
constexpr size_t SZ_XMID  = (size_t)M1_C * H_C * 4;
constexpr size_t OFF_XW2  = OFF_XMID + SZ_XMID;                  // f32 [M1][20]
constexpr size_t SZ_XW2   = (size_t)M1_C * 20 * 4;
constexpr size_t OFF_W2T  = OFF_XW2 + SZ_XW2;                    // f32 [20][512]
constexpr size_t SZ_W2T   = (size_t)20 * H_C * 4;
constexpr size_t OFF_CNT  = OFF_W2T + SZ_W2T;                    // u32 flags, one per 64B line

// ---- helpers ----
DEVINL unsigned short f2bf(float f) {
  unsigned u = __builtin_bit_cast(unsigned, f);
  u += 0x7fffu + ((u >> 16) & 1u);          // RNE
  return (unsigned short)(u >> 16);
}
DEVINL float sigm(float x) {
  return __builtin_amdgcn_rcpf(1.f + __builtin_amdgcn_exp2f(-1.4426950408889634f * x));
}
DEVINL float tanh_(float x) {
  return 2.f * __builtin_amdgcn_rcpf(1.f + __builtin_amdgcn_exp2f(-2.8853900817779268f * x)) - 1.f;
}
DEVINL void gl_lds16(const void* g, void* l) {
  __builtin_amdgcn_global_load_lds((const __attribute__((address_space(1))) void*)g,
                                   (__attribute__((address_space(3))) void*)l, 16, 0, 0);
}
DEVINL void gl_lds16_coh(const void* g, void* l) {   // SC0|SC1: bypass non-coherent L2, read at IC
  __builtin_amdgcn_global_load_lds((const __attribute__((address_space(1))) void*)g,
                                   (__attribute__((address_space(3))) void*)l, 16, 0, 17);
}

// ================= pack (A + all weights, single launch) =================

__global__ void pack_all(const float* __restrict__ img, const float* __restrict__ lbl,
                         const float* __restrict__ W1, const float* __restrict__ U1,
                         const float* __restrict__ W2,
                         unsigned short* __restrict__ A,
                         unsigned short* __restrict__ W1T, unsigned short* __restrict__ U1T,
                         float* __restrict__ W2T) {
  int gid = blockIdx.x * blockDim.x + threadIdx.x;
  constexpr int CPR = KP_C / 8;                       // 100 chunks per A row
  constexpr int NA  = M1_C * CPR;                     // 2,816,000
  constexpr int N1  = G4_C * KP_C;                    // 1,638,400
  constexpr int N2  = G4_C * H_C;                     // 1,048,576
  constexpr int N3  = 20 * H_C;                       // 10,240

  if (gid < NA) {
    // ---- A[r][0..799] bf16: r = t*512+b
    int r  = gid / CPR;
    int cc = gid - r * CPR;
    int t = r >> 9, b = r & 511;
    int k1 = t / 5, n = t - k1 * 5;
    int c0 = cc * 8;
    ushort8 v;
    if (c0 + 8 <= DIMS_C) {
      const float* p = img + ((size_t)((b * 11 + k1) * 5 + n)) * DIMS_C + c0;
      f32x4 x0 = *(const f32x4*)(p);
      f32x4 x1 = *(const f32x4*)(p + 4);
#pragma unroll
      for (int j = 0; j < 4; ++j) { v[j] = f2bf(x0[j]); v[4 + j] = f2bf(x1[j]); }
    } else {
#pragma unroll
      for (int j = 0; j < 8; ++j) {
        int c = c0 + j;
        float x = 0.f;
        if (c < DIMS_C) x = img[((size_t)((b * 11 + k1) * 5 + n)) * DIMS_C + c];
        else if (c < I0_C && k1 < 10) x = lbl[((size_t)((b * 11 + k1) * 5 + n)) * 5 + (c - DIMS_C)];
        v[j] = f2bf(x);
      }
    }
    *(ushort8*)(A + (size_t)r * KP_C + c0) = v;
  } else if (gid < NA + N1) {
    int g1 = gid - NA;
    int col = g1 / KP_C, k = g1 - col * KP_C;
    float x = (k < I0_C) ? W1[(size_t)k * G4_C + col] : 0.f;
    W1T[(size_t)col * KP_C + k] = f2bf(x);
  } else if (gid < NA + N1 + N2) {
    int g2 = gid - NA - N1;
    int col = g2 / H_C, k = g2 - col * H_C;
    U1T[(size_t)col * H_C + k] = f2bf(U1[(size_t)k * G4_C + col]);
  } else if (gid < NA + N1 + N2 + N3) {
    int g3 = gid - NA - N1 - N2;
    int col = g3 / H_C, k = g3 - col * H_C;
    W2T[(size_t)col * H_C + k] = W2[(size_t)k * 20 + col];
  }
}

// ================= gemm1: xw1 = A @ W1 + b1  (r8-proven: BK=32, 2-phase, 2 blk/CU) =
// Epilogue: quad-pack via shfl butterflies -> 16 x 8B stores/lane (was 64 x 2B).
__launch_bounds__(256, 2)
__global__ void gemm1(const unsigned short* __restrict__ A,
                      const unsigned short* __restrict__ Bt,
                      const float* __restrict__ bias,
                      _Float16* __restrict__ C)
{
  __shared__ unsigned short sA[2][128 * 32];
  __shared__ unsigned short sB[2][128 * 32];
  const int tid = threadIdx.x;
  const int w = tid >> 6, l = tid & 63;
  const int lo = l & 15, hi = l >> 4;
  const int wm = w >> 1, wn = w & 1;
  const int id = blockIdx.x;
  const int swz = (id & 7) * 440 + (id >> 3);   // XCD chunked, bijective (3520 % 8 == 0)
  const int by = swz >> 4;                      // 0..219  (M tiles)
  const int bx = swz & 15;                      // 0..15   (N tiles)

  const unsigned short* aSrc[2];
  const unsigned short* bSrc[2];
#pragma unroll
  for (int q = 0; q < 2; ++q) {
    int row = w * 32 + q * 16 + (l >> 2);
    int ch = l & 3;
    int sw = (row >> 1) & 3;
    aSrc[q] = A  + (size_t)(by * 128 + row) * KP_C + (ch ^ sw) * 8;
    bSrc[q] = Bt + (size_t)(bx * 128 + row) * KP_C + (ch ^ sw) * 8;
  }
  int aOff[4], bOff[4];
#pragma unroll
  for (int i = 0; i < 4; ++i) {
    int rA = wm * 64 + i * 16 + lo;
    aOff[i] = rA * 32 + ((hi ^ ((rA >> 1) & 3)) * 8);
    int rB = wn * 64 + i * 16 + lo;
    bOff[i] = rB * 32 + ((hi ^ ((rB >> 1) & 3)) * 8);
  }

  f32x4 acc[4][4];
#pragma unroll
  for (int i = 0; i < 4; ++i)
#pragma unroll
    for (int j = 0; j < 4; ++j) acc[i][j] = (f32x4){0.f, 0.f, 0.f, 0.f};

#define G1_STAGE(buf, ks)                                                  \
  {                                                                        \
    _Pragma("unroll")                                                      \
    for (int q = 0; q < 2; ++q) {                                          \
      gl_lds16(aSrc[q] + (ks) * 32, &sA[buf][w * 1024 + q * 512]);         \
      gl_lds16(bSrc[q] + (ks) * 32, &sB[buf][w * 1024 + q * 512]);         \
    }                                                                      \
  }

  G1_STAGE(0, 0);
  asm volatile("s_waitcnt vmcnt(0)" ::: "memory");
  __syncthreads();

  int cur = 0;
#pragma unroll 1
  for (int ks = 0; ks < KP_C / 32; ++ks) {
    if (ks < KP_C / 32 - 1) G1_STAGE(cur ^ 1, ks + 1);
    bf16x8 af[4], bfr[4];
#pragma unroll
    for (int i = 0; i < 4; ++i) {
      af[i]  = *(const bf16x8*)(&sA[cur][0] + aOff[i]);
      bfr[i] = *(const bf16x8*)(&sB[cur][0] + bOff[i]);
    }
#pragma unroll
    for (int mi = 0; mi < 4; ++mi)
#pragma unroll
      for (int ni = 0; ni < 4; ++ni)
        acc[mi][ni] = __builtin_amdgcn_mfma_f32_16x16x32_bf16(af[mi], bfr[ni], acc[mi][ni], 0, 0, 0);
    asm volatile("s_waitcnt vmcnt(0)" ::: "memory");
    __syncthreads();
    cur ^= 1;
  }
#undef G1_STAGE

  // epilogue: bias add -> fp16 pair pack (shfl_xor 1) -> quad gather (shfl_xor 2)
  // -> lanes lo%4==0 store 8B (cols lo..lo+3). 16 stores/lane instead of 64.
  const size_t crow0 = (size_t)by * 128 + wm * 64;
  const int ccol0 = bx * 128 + wn * 64;
#pragma unroll
  for (int ni = 0; ni < 4; ++ni) {
    int col = ccol0 + ni * 16 + lo;
    float bv = bias[col];
#pragma unroll
    for (int mi = 0; mi < 4; ++mi) {
#pragma unroll
      for (int j = 0; j < 4; ++j) {
        size_t row = crow0 + mi * 16 + hi * 4 + j;
        float v = acc[mi][ni][j] + bv;
        float o = __shfl_xor(v, 1);
        unsigned u0 = (unsigned)__builtin_bit_cast(unsigned short, (_Float16)v) |
                      ((unsigned)__builtin_bit_cast(unsigned short, (_Float16)o) << 16);
        unsigned u1 = __shfl_xor(u0, 2);
        if ((lo & 3) == 0) {
          unsigned long long uv = (unsigned long long)u0 | ((unsigned long long)u1 << 32);
          *(unsigned long long*)(C + row * G4_C + col) = uv;
        }
      }
    }
  }
}

// ================= lstm1: persistent recurrence, 512 blocks / 2 per CU ============
// (r8-proven config, measured ~160 us x6.) 32 batch-groups (16 rows) x 16 unit-
// groups (32 units). U1 slice is 128 VGPR/lane by construction -> this is the
// finest block split that stays co-resident without spill or traffic duplication.
__launch_bounds__(256, 2)
__global__ void lstm1(const _Float16* __restrict__ xw,        // [M1][2048]
                      const unsigned short* __restrict__ U1T, // [2048 cols][512 k] bf16
                      unsigned short* __restrict__ hbuf,      // [2][512][512] bf16
                      float* __restrict__ xmid,               // [M1][512]
                      unsigned int* __restrict__ cnt)         // flag (bg,cg) at [(bg*16+cg)*16]
{
  __shared__ unsigned short sH[16 * 512];   // 16 KB; [row][chunk c] = global chunk c^(row&7)
  __shared__ float sG[4 * 16 * 32];         // 8 KB gate exchange

  const int tid = threadIdx.x;
  const int g = tid >> 6;                   // wave = gate
  const int l = tid & 63;
  const int lo = l & 15, hi = l >> 4;
  const int bg = blockIdx.x >> 4;           // 0..31
  const int cg = blockIdx.x & 15;
  const int brow0 = bg * 16;
  const int ub = cg * 32;

  // U1 B-fragments for this gate: bu[nf][kk], unit = ub+nf*16+lo, k = kk*32+hi*8+i
  bf16x8 bu[2][16];
#pragma unroll
  for (int nf = 0; nf < 2; ++nf) {
    const unsigned short* src = U1T + ((size_t)(g * H_C + ub + nf * 16 + lo)) * H_C + hi * 8;
#pragma unroll
    for (int kk = 0; kk < 16; ++kk)
      bu[nf][kk] = *(const bf16x8*)(src + kk * 32);
  }

  // A-frag addressing: row = lo (16 rows), stage pre-swizzled by row&7
  const int s0 = lo & 7;
  const int aO0 = lo * 1024;

  // cell ownership: rows rbase..rbase+1, unit u
  const int half = l >> 5;
  const int u = l & 31;
  const int rbase = g * 4 + half * 2;
  const int uread = u ^ (g << 3);           // row>>2 == g for owned rows

  float c_st[2] = {0.f, 0.f};

  // xw for t=0
  const _Float16* xb = xw + (size_t)(brow0 + rbase) * G4_C + ub + u;
  float xwv[4][2];
#pragma unroll
  for (int g2 = 0; g2 < 4; ++g2)
#pragma unroll
    for (int j = 0; j < 2; ++j)
      xwv[g2][j] = (float)xb[(size_t)j * G4_C + g2 * H_C];

#pragma unroll 1
  for (int t = 0; t < T_C; ++t) {
    f32x4 acc[2];
    acc[0] = (f32x4){0.f, 0.f, 0.f, 0.f};
    acc[1] = (f32x4){0.f, 0.f, 0.f, 0.f};

    if (t > 0) {
      // ---- per-wave poll: 16 flags, each in its own 64B line
      {
        const unsigned* fp = cnt + (size_t)(bg * 16 + (l & 15)) * 16;
        unsigned target = (unsigned)t;
        while (true) {
          unsigned v = __hip_atomic_load(fp, RLX, AGT);
          if (__all(v >= target)) break;
          __builtin_amdgcn_s_sleep(1);
        }
      }
      asm volatile("" ::: "memory");   // keep gl_lds below the poll

      // ---- stage h(t): wave g stages rows g*4..g*4+3, source pre-swizzled (l^(row&7))
      const unsigned short* hsrc = hbuf + (size_t)(t & 1) * (B_C * H_C);
#pragma unroll
      for (int p = 0; p < 4; ++p) {
        int row = g * 4 + p;
        gl_lds16_coh(hsrc + (size_t)(brow0 + row) * H_C + ((l ^ (row & 7)) * 8),
                     sH + row * 512);
      }
      asm volatile("s_waitcnt vmcnt(0)" ::: "memory");
      __syncthreads();

      // ---- z(gate g) = h @ U1 : M=16 x N=32 x K=512
#pragma unroll
      for (int kk = 0; kk < 16; ++kk) {
        int off = (((kk * 4 + hi) ^ s0) << 4);
        bf16x8 a0 = *(const bf16x8*)((const char*)sH + aO0 + off);
        acc[0] = __builtin_amdgcn_mfma_f32_16x16x32_bf16(a0, bu[0][kk], acc[0], 0, 0, 0);
        acc[1] = __builtin_amdgcn_mfma_f32_16x16x32_bf16(a0, bu[1][kk], acc[1], 0, 0, 0);
      }
    }

    // ---- write this gate's z tile to sG (swizzled unit index)
#pragma unroll
    for (int nf = 0; nf < 2; ++nf)
#pragma unroll
      for (int j = 0; j < 4; ++j) {
        int row = hi * 4 + j;
        sG[g * 512 + row * 32 + ((nf * 16 + lo) ^ (hi << 3))] = acc[nf][j];
      }
    __syncthreads();

    // ---- gather 4 gates, activate, update state (2 cells/thread)
    float hnew[2];
#pragma unroll
    for (int j = 0; j < 2; ++j) {
      int r = rbase + j;
      float zi = sG[0 * 512 + r * 32 + uread] + xwv[0][j];
      float zf = sG[1 * 512 + r * 32 + uread] + xwv[1][j];
      float zg = sG[2 * 512 + r * 32 + uread] + xwv[2][j];
      float zo = sG[3 * 512 + r * 32 + uread] + xwv[3][j];
      float iv = sigm(zi), fv = sigm(zf), gv = tanh_(zg), ov = sigm(zo);
      float cv = fv * c_st[j] + iv * gv;
      c_st[j] = cv;
      hnew[j] = ov * tanh_(cv);
    }

    if (t < T_C - 1) {
      // ---- h(t+1) coherent packed-u32 stores (wide: 32 lanes/wave active)
      unsigned short* hd = hbuf + (size_t)((t & 1) ^ 1) * (B_C * H_C);
#pragma unroll
      for (int j = 0; j < 2; ++j) {
        float other = __shfl_xor(hnew[j], 1);
        if ((u & 1) == 0) {
          unsigned val = (unsigned)f2bf(hnew[j]) | ((unsigned)f2bf(other) << 16);
          __hip_atomic_store((unsigned*)(hd + (size_t)(brow0 + rbase + j) * H_C + ub + u), val,
                             RLX, AGT);
        }
      }

      // drains every thread's h stores (vmcnt ack = IC visibility), then signal
      __syncthreads();
      if (tid == 0)
        __hip_atomic_store(&cnt[(size_t)(bg * 16 + cg) * 16], (unsigned)(t + 1), RLX, AGT);

      // ---- off-critical-path: xmid (NT) + xw(t+1) prefetch overlap the next poll
#pragma unroll
      for (int j = 0; j < 2; ++j)
        __builtin_nontemporal_store(hnew[j],
            &xmid[((size_t)t * B_C + brow0 + rbase + j) * H_C + ub + u]);
      const _Float16* xp = xb + (size_t)(t + 1) * B_C * G4_C;
#pragma unroll
      for (int g2 = 0; g2 < 4; ++g2)
#pragma unroll
        for (int j = 0; j < 2; ++j)
          xwv[g2][j] = (float)xp[(size_t)j * G4_C + g2 * H_C];
    } else {
#pragma unroll
      for (int j = 0; j < 2; ++j)
        __builtin_nontemporal_store(hnew[j],
            &xmid[((size_t)t * B_C + brow0 + rbase + j) * H_C + ub + u]);
    }
  }
}

// ================= gemm2: xw2 = x_mid @ W2 + b2 (fp32, 1 wave/row, split-K) ========
// Lane l covers k = l*8..l*8+7 (coalesced 2KB/row, X read exactly once), 20 partial
// dots in regs, 6-round butterfly reduce, lanes 0..4 write the 80B output row.
__global__ void gemm2(const float* __restrict__ X,    // [M1][512]
                      const float* __restrict__ W2T,  // [20][512]
                      const float* __restrict__ b2,   // [20]
                      float* __restrict__ XW2)        // [M1][20]
{
  int wid = (blockIdx.x * blockDim.x + threadIdx.x) >> 6;   // wave id = row
  if (wid >= M1_C) return;
  int l = threadIdx.x & 63;
  const float* xr = X + (size_t)wid * H_C + l * 8;
  f32x4 x0 = *(const f32x4*)(xr);
  f32x4 x1 = *(const f32x4*)(xr + 4);
  float acc[20];
#pragma unroll
  for (int j = 0; j < 20; ++j) {
    const float* wr = W2T + (size_t)j * H_C + l * 8;
    f32x4 w0 = *(const f32x4*)(wr);
    f32x4 w1 = *(const f32x4*)(wr + 4);
    acc[j] = x0[0]*w0[0] + x0[1]*w0[1] + x0[2]*w0[2] + x0[3]*w0[3]
           + x1[0]*w1[0] + x1[1]*w1[1] + x1[2]*w1[2] + x1[3]*w1[3];
  }
#pragma unroll
  for (int off = 32; off >= 1; off >>= 1)
#pragma unroll
    for (int j = 0; j < 20; ++j)
      acc[j] += __shfl_xor(acc[j], off);
  if (l < 5) {
    f32x4 o;
#pragma unroll
    for (int q = 0; q < 4; ++q) o[q] = acc[l * 4 + q] + b2[l * 4 + q];
    *(f32x4*)(XW2 + (size_t)wid * 20 + l * 4) = o;
  }
}

// ================= lstm2: tiny recurrence, fp32 =============
__global__ void lstm2(const float* __restrict__ XW2,  // [M1][20]
                      const float* __restrict__ U2,   // [5][20]
                      float* __restrict__ out)        // [512][11][5][5]
{
  int b = blockIdx.x * blockDim.x + threadIdx.x;
  if (b >= B_C) return;
  float u2[5][20];
#pragma unroll
  for (int k = 0; k < 5; ++k)
#pragma unroll
    for (int j = 0; j < 20; ++j) u2[k][j] = U2[k * 20 + j];
  float h[5] = {0, 0, 0, 0, 0}, c[5] = {0, 0, 0, 0, 0};
  for (int t = 0; t < T_C; ++t) {
    const float* xr = XW2 + ((size_t)t * B_C + b) * 20;
    float z[20];
#pragma unroll
    for (int j = 0; j < 20; ++j) z[j] = xr[j];
#pragma unroll
    for (int k = 0; k < 5; ++k) {
      float hk = h[k];
#pragma unroll
      for (int j = 0; j < 20; ++j) z[j] += hk * u2[k][j];
    }
#pragma unroll
    for (int n = 0; n < 5; ++n) {
      float iv = sigm(z[n]), fv = sigm(z[5 + n]), gv = tanh_(z[10 + n]), ov = sigm(z[15 + n]);
      c[n] = fv * c[n] + iv * gv;
      h[n] = ov * tanh_(c[n]);
    }
    int k1 = t / 5, nn = t - k1 * 5;
    float* op = out + (((size_t)b * 11 + k1) * 5 + nn) * 5;
#pragma unroll
    for (int j = 0; j < 5; ++j) op[j] = h[j];
  }
}

// ================= launch =================
extern "C" void kernel_launch(void* const* d_in, const int* in_sizes, int n_in,
                              void* d_out, int out_size, void* d_ws, size_t ws_size,
                              hipStream_t stream) {
  (void)in_sizes; (void)n_in; (void)out_size; (void)ws_size;
  const float* img = (const float*)d_in[0];
  const float* lbl = (const float*)d_in[1];
  const float* W1  = (const float*)d_in[2];
  const float* U1  = (const float*)d_in[3];
  const float* b1  = (const float*)d_in[4];
  const float* W2  = (const float*)d_in[5];
  const float* U2  = (const float*)d_in[6];
  const float* b2  = (const float*)d_in[7];

  char* ws = (char*)d_ws;
  unsigned short* A    = (unsigned short*)(ws + OFF_A);
  unsigned short* W1T  = (unsigned short*)(ws + OFF_W1T);
  unsigned short* U1T  = (unsigned short*)(ws + OFF_U1T);
  _Float16*       XW1  = (_Float16*)      (ws + OFF_XW1);
  unsigned short* HB   = (unsigned short*)(ws + OFF_H);
  float*          XMID = (float*)         (ws + OFF_XMID);
  float*          XW2  = (float*)         (ws + OFF_XW2);
  float*          W2T  = (float*)         (ws + OFF_W2T);
  unsigned int*   CNT  = (unsigned int*)  (ws + OFF_CNT);

  hipMemsetAsync(CNT, 0, 512 * 64, stream);               // 512 flags, one per 64B line

  {
    constexpr int NTOT = M1_C * (KP_C / 8) + G4_C * KP_C + G4_C * H_C + 20 * H_C;
    pack_all<<<(NTOT + 255) / 256, 256, 0, stream>>>(img, lbl, W1, U1, W2, A, W1T, U1T, W2T);
  }

  gemm1<<<3520, 256, 0, stream>>>(A, W1T, b1, XW1);
  lstm1<<<512, 256, 0, stream>>>(XW1, U1T, HB, XMID, CNT);
  gemm2<<<(M1_C * 64) / 256, 256, 0, stream>>>(XMID, W2T, b2, XW2);
  lstm2<<<8, 64, 0, stream>>>(XW2, U2, (float*)d_out);
}

// Round 18
// 421.410 us; speedup vs baseline: 1.0550x; 1.0550x over previous
//
#include <hip/hip_runtime.h>

typedef __attribute__((ext_vector_type(8))) __bf16 bf16x8;
typedef __attribute__((ext_vector_type(8))) unsigned short ushort8;
typedef __attribute__((ext_vector_type(4))) float f32x4;
typedef __attribute__((ext_vector_type(2))) unsigned long long u64x2;

#define DEVINL __device__ __forceinline__
#define RLX __ATOMIC_RELAXED
#define AGT __HIP_MEMORY_SCOPE_AGENT

constexpr int B_C    = 512;
constexpr int DIMS_C = 784;
constexpr int T_C    = 55;      // K1*N time steps
constexpr int I0_C   = 789;     // DIMS + N
constexpr int KP_C   = 800;     // padded K for gemm1 (25 * 32)
constexpr int H_C    = 512;
constexpr int G4_C   = 2048;    // 4*H
constexpr int M1_C   = 28160;   // T_C * B_C, rows ordered r = t*512 + b

// ---- workspace layout (bytes, all 256-aligned) ----
constexpr size_t OFF_A    = 0;                                   // bf16 [M1][KP]
constexpr size_t SZ_A     = (size_t)M1_C * KP_C * 2;
constexpr size_t OFF_W1T  = OFF_A + SZ_A;                        // bf16 [2048][KP]
constexpr size_t SZ_W1T   = (size_t)G4_C * KP_C * 2;
constexpr size_t OFF_U1T  = OFF_W1T + SZ_W1T;                    // bf16 [2048][512]
constexpr size_t SZ_U1T   = (size_t)G4_C * H_C * 2;
constexpr size_t OFF_XW1  = OFF_U1T + SZ_U1T;                    // fp16 [M1][2048]
constexpr size_t SZ_XW1   = (size_t)M1_C * G4_C * 2;
constexpr size_t OFF_H    = OFF_XW1 + SZ_XW1;                    // bf16 [2][512][512]
constexpr size_t SZ_H     = (size_t)2 * B_C * H_C * 2;
constexpr size_t OFF_XMID = OFF_H + SZ_H;                        // f32 [M1][512]
constexpr size_t SZ_XMID  = (size_t)M1_C * H_C * 4;
constexpr size_t OFF_XW2  = OFF_XMID + SZ_XMID;                  // f32 [M1][20]
constexpr size_t SZ_XW2   = (size_t)M1_C * 20 * 4;
constexpr size_t OFF_W2T  = OFF_XW2 + SZ_XW2;                    // f32 [20][512]
constexpr size_t SZ_W2T   = (size_t)20 * H_C * 4;
constexpr size_t OFF_CNT  = OFF_W2T + SZ_W2T;                    // u32 flags, one per 64B line

// ---- helpers ----
DEVINL unsigned short f2bf(float f) {
  unsigned u = __builtin_bit_cast(unsigned, f);
  u += 0x7fffu + ((u >> 16) & 1u);          // RNE
  return (unsigned short)(u >> 16);
}
DEVINL float sigm(float x) {
  return __builtin_amdgcn_rcpf(1.f + __builtin_amdgcn_exp2f(-1.4426950408889634f * x));
}
DEVINL float tanh_(float x) {
  return 2.f * __builtin_amdgcn_rcpf(1.f + __builtin_amdgcn_exp2f(-2.8853900817779268f * x)) - 1.f;
}
DEVINL void gl_lds16(const void* g, void* l) {
  __builtin_amdgcn_global_load_lds((const __attribute__((address_space(1))) void*)g,
                                   (__attribute__((address_space(3))) void*)l, 16, 0, 0);
}
DEVINL void gl_lds16_coh(const void* g, void* l) {   // SC0|SC1: bypass non-coherent L2, read at IC
  __builtin_amdgcn_global_load_lds((const __attribute__((address_space(1))) void*)g,
                                   (__attribute__((address_space(3))) void*)l, 16, 0, 17);
}

// ================= pack (A + all weights, single launch) =================

__global__ void pack_all(const float* __restrict__ img, const float* __restrict__ lbl,
                         const float* __restrict__ W1, const float* __restrict__ U1,
                         const float* __restrict__ W2,
                         unsigned short* __restrict__ A,
                         unsigned short* __restrict__ W1T, unsigned short* __restrict__ U1T,
                         float* __restrict__ W2T) {
  int gid = blockIdx.x * blockDim.x + threadIdx.x;
  constexpr int CPR = KP_C / 8;                       // 100 chunks per A row
  constexpr int NA  = M1_C * CPR;                     // 2,816,000
  constexpr int N1  = G4_C * KP_C;                    // 1,638,400
  constexpr int N2  = G4_C * H_C;                     // 1,048,576
  constexpr int N3  = 20 * H_C;                       // 10,240

  if (gid < NA) {
    // ---- A[r][0..799] bf16: r = t*512+b
    int r  = gid / CPR;
    int cc = gid - r * CPR;
    int t = r >> 9, b = r & 511;
    int k1 = t / 5, n = t - k1 * 5;
    int c0 = cc * 8;
    ushort8 v;
    if (c0 + 8 <= DIMS_C) {
      const float* p = img + ((size_t)((b * 11 + k1) * 5 + n)) * DIMS_C + c0;
      f32x4 x0 = *(const f32x4*)(p);
      f32x4 x1 = *(const f32x4*)(p + 4);
#pragma unroll
      for (int j = 0; j < 4; ++j) { v[j] = f2bf(x0[j]); v[4 + j] = f2bf(x1[j]); }
    } else {
#pragma unroll
      for (int j = 0; j < 8; ++j) {
        int c = c0 + j;
        float x = 0.f;
        if (c < DIMS_C) x = img[((size_t)((b * 11 + k1) * 5 + n)) * DIMS_C + c];
        else if (c < I0_C && k1 < 10) x = lbl[((size_t)((b * 11 + k1) * 5 + n)) * 5 + (c - DIMS_C)];
        v[j] = f2bf(x);
      }
    }
    *(ushort8*)(A + (size_t)r * KP_C + c0) = v;
  } else if (gid < NA + N1) {
    int g1 = gid - NA;
    int col = g1 / KP_C, k = g1 - col * KP_C;
    float x = (k < I0_C) ? W1[(size_t)k * G4_C + col] : 0.f;
    W1T[(size_t)col * KP_C + k] = f2bf(x);
  } else if (gid < NA + N1 + N2) {
    int g2 = gid - NA - N1;
    int col = g2 / H_C, k = g2 - col * H_C;
    U1T[(size_t)col * H_C + k] = f2bf(U1[(size_t)k * G4_C + col]);
  } else if (gid < NA + N1 + N2 + N3) {
    int g3 = gid - NA - N1 - N2;
    int col = g3 / H_C, k = g3 - col * H_C;
    W2T[(size_t)col * H_C + k] = W2[(size_t)k * 20 + col];
  }
}

// ================= gemm1: xw1 = A @ W1 + b1  (r8-proven: BK=32, 2-phase, 2 blk/CU) =
// Epilogue: scalar fp16 stores (r16-proven) in ROW-MAJOR order (mi,j outer, ni
// inner) so each row's four 32B segments are issued back-to-back -> L2 write
// coalescing, no partial-line RMW amplification (r17 counter evidence: 226MB).
__launch_bounds__(256, 2)
__global__ void gemm1(const unsigned short* __restrict__ A,
                      const unsigned short* __restrict__ Bt,
                      const float* __restrict__ bias,
                      _Float16* __restrict__ C)
{
  __shared__ unsigned short sA[2][128 * 32];
  __shared__ unsigned short sB[2][128 * 32];
  const int tid = threadIdx.x;
  const int w = tid >> 6, l = tid & 63;
  const int lo = l & 15, hi = l >> 4;
  const int wm = w >> 1, wn = w & 1;
  const int id = blockIdx.x;
  const int swz = (id & 7) * 440 + (id >> 3);   // XCD chunked, bijective (3520 % 8 == 0)
  const int by = swz >> 4;                      // 0..219  (M tiles)
  const int bx = swz & 15;                      // 0..15   (N tiles)

  const unsigned short* aSrc[2];
  const unsigned short* bSrc[2];
#pragma unroll
  for (int q = 0; q < 2; ++q) {
    int row = w * 32 + q * 16 + (l >> 2);
    int ch = l & 3;
    int sw = (row >> 1) & 3;
    aSrc[q] = A  + (size_t)(by * 128 + row) * KP_C + (ch ^ sw) * 8;
    bSrc[q] = Bt + (size_t)(bx * 128 + row) * KP_C + (ch ^ sw) * 8;
  }
  int aOff[4], bOff[4];
#pragma unroll
  for (int i = 0; i < 4; ++i) {
    int rA = wm * 64 + i * 16 + lo;
    aOff[i] = rA * 32 + ((hi ^ ((rA >> 1) & 3)) * 8);
    int rB = wn * 64 + i * 16 + lo;
    bOff[i] = rB * 32 + ((hi ^ ((rB >> 1) & 3)) * 8);
  }

  f32x4 acc[4][4];
#pragma unroll
  for (int i = 0; i < 4; ++i)
#pragma unroll
    for (int j = 0; j < 4; ++j) acc[i][j] = (f32x4){0.f, 0.f, 0.f, 0.f};

#define G1_STAGE(buf, ks)                                                  \
  {                                                                        \
    _Pragma("unroll")                                                      \
    for (int q = 0; q < 2; ++q) {                                          \
      gl_lds16(aSrc[q] + (ks) * 32, &sA[buf][w * 1024 + q * 512]);         \
      gl_lds16(bSrc[q] + (ks) * 32, &sB[buf][w * 1024 + q * 512]);         \
    }                                                                      \
  }

  G1_STAGE(0, 0);
  asm volatile("s_waitcnt vmcnt(0)" ::: "memory");
  __syncthreads();

  int cur = 0;
#pragma unroll 1
  for (int ks = 0; ks < KP_C / 32; ++ks) {
    if (ks < KP_C / 32 - 1) G1_STAGE(cur ^ 1, ks + 1);
    bf16x8 af[4], bfr[4];
#pragma unroll
    for (int i = 0; i < 4; ++i) {
      af[i]  = *(const bf16x8*)(&sA[cur][0] + aOff[i]);
      bfr[i] = *(const bf16x8*)(&sB[cur][0] + bOff[i]);
    }
#pragma unroll
    for (int mi = 0; mi < 4; ++mi)
#pragma unroll
      for (int ni = 0; ni < 4; ++ni)
        acc[mi][ni] = __builtin_amdgcn_mfma_f32_16x16x32_bf16(af[mi], bfr[ni], acc[mi][ni], 0, 0, 0);
    asm volatile("s_waitcnt vmcnt(0)" ::: "memory");
    __syncthreads();
    cur ^= 1;
  }
#undef G1_STAGE

  // epilogue: row-major store order; bias preloaded per ni
  const size_t crow0 = (size_t)by * 128 + wm * 64;
  const int ccol0 = bx * 128 + wn * 64;
  float bv[4];
#pragma unroll
  for (int ni = 0; ni < 4; ++ni) bv[ni] = bias[ccol0 + ni * 16 + lo];
#pragma unroll
  for (int mi = 0; mi < 4; ++mi) {
#pragma unroll
    for (int j = 0; j < 4; ++j) {
      size_t row = crow0 + mi * 16 + hi * 4 + j;
      _Float16* cr = C + row * G4_C + ccol0 + lo;
#pragma unroll
      for (int ni = 0; ni < 4; ++ni)
        cr[ni * 16] = (_Float16)(acc[mi][ni][j] + bv[ni]);
    }
  }
}

// ================= lstm1: persistent recurrence, 512 blocks / 2 per CU ============
// (r8-proven config, measured ~160 us x7.) 32 batch-groups (16 rows) x 16 unit-
// groups (32 units). U1 slice is 128 VGPR/lane by construction -> this is the
// finest block split that stays co-resident without spill or traffic duplication.
__launch_bounds__(256, 2)
__global__ void lstm1(const _Float16* __restrict__ xw,        // [M1][2048]
                      const unsigned short* __restrict__ U1T, // [2048 cols][512 k] bf16
                      unsigned short* __restrict__ hbuf,      // [2][512][512] bf16
                      float* __restrict__ xmid,               // [M1][512]
                      unsigned int* __restrict__ cnt)         // flag (bg,cg) at [(bg*16+cg)*16]
{
  __shared__ unsigned short sH[16 * 512];   // 16 KB; [row][chunk c] = global chunk c^(row&7)
  __shared__ float sG[4 * 16 * 32];         // 8 KB gate exchange

  const int tid = threadIdx.x;
  const int g = tid >> 6;                   // wave = gate
  const int l = tid & 63;
  const int lo = l & 15, hi = l >> 4;
  const int bg = blockIdx.x >> 4;           // 0..31
  const int cg = blockIdx.x & 15;
  const int brow0 = bg * 16;
  const int ub = cg * 32;

  // U1 B-fragments for this gate: bu[nf][kk], unit = ub+nf*16+lo, k = kk*32+hi*8+i
  bf16x8 bu[2][16];
#pragma unroll
  for (int nf = 0; nf < 2; ++nf) {
    const unsigned short* src = U1T + ((size_t)(g * H_C + ub + nf * 16 + lo)) * H_C + hi * 8;
#pragma unroll
    for (int kk = 0; kk < 16; ++kk)
      bu[nf][kk] = *(const bf16x8*)(src + kk * 32);
  }

  // A-frag addressing: row = lo (16 rows), stage pre-swizzled by row&7
  const int s0 = lo & 7;
  const int aO0 = lo * 1024;

  // cell ownership: rows rbase..rbase+1, unit u
  const int half = l >> 5;
  const int u = l & 31;
  const int rbase = g * 4 + half * 2;
  const int uread = u ^ (g << 3);           // row>>2 == g for owned rows

  float c_st[2] = {0.f, 0.f};

  // xw for t=0
  const _Float16* xb = xw + (size_t)(brow0 + rbase) * G4_C + ub + u;
  float xwv[4][2];
#pragma unroll
  for (int g2 = 0; g2 < 4; ++g2)
#pragma unroll
    for (int j = 0; j < 2; ++j)
      xwv[g2][j] = (float)xb[(size_t)j * G4_C + g2 * H_C];

#pragma unroll 1
  for (int t = 0; t < T_C; ++t) {
    f32x4 acc[2];
    acc[0] = (f32x4){0.f, 0.f, 0.f, 0.f};
    acc[1] = (f32x4){0.f, 0.f, 0.f, 0.f};

    if (t > 0) {
      // ---- per-wave poll: 16 flags, each in its own 64B line
      {
        const unsigned* fp = cnt + (size_t)(bg * 16 + (l & 15)) * 16;
        unsigned target = (unsigned)t;
        while (true) {
          unsigned v = __hip_atomic_load(fp, RLX, AGT);
          if (__all(v >= target)) break;
          __builtin_amdgcn_s_sleep(1);
        }
      }
      asm volatile("" ::: "memory");   // keep gl_lds below the poll

      // ---- stage h(t): wave g stages rows g*4..g*4+3, source pre-swizzled (l^(row&7))
      const unsigned short* hsrc = hbuf + (size_t)(t & 1) * (B_C * H_C);
#pragma unroll
      for (int p = 0; p < 4; ++p) {
        int row = g * 4 + p;
        gl_lds16_coh(hsrc + (size_t)(brow0 + row) * H_C + ((l ^ (row & 7)) * 8),
                     sH + row * 512);
      }
      asm volatile("s_waitcnt vmcnt(0)" ::: "memory");
      __syncthreads();

      // ---- z(gate g) = h @ U1 : M=16 x N=32 x K=512
#pragma unroll
      for (int kk = 0; kk < 16; ++kk) {
        int off = (((kk * 4 + hi) ^ s0) << 4);
        bf16x8 a0 = *(const bf16x8*)((const char*)sH + aO0 + off);
        acc[0] = __builtin_amdgcn_mfma_f32_16x16x32_bf16(a0, bu[0][kk], acc[0], 0, 0, 0);
        acc[1] = __builtin_amdgcn_mfma_f32_16x16x32_bf16(a0, bu[1][kk], acc[1], 0, 0, 0);
      }
    }

    // ---- write this gate's z tile to sG (swizzled unit index)
#pragma unroll
    for (int nf = 0; nf < 2; ++nf)
#pragma unroll
      for (int j = 0; j < 4; ++j) {
        int row = hi * 4 + j;
        sG[g * 512 + row * 32 + ((nf * 16 + lo) ^ (hi << 3))] = acc[nf][j];
      }
    __syncthreads();

    // ---- gather 4 gates, activate, update state (2 cells/thread)
    float hnew[2];
#pragma unroll
    for (int j = 0; j < 2; ++j) {
      int r = rbase + j;
      float zi = sG[0 * 512 + r * 32 + uread] + xwv[0][j];
      float zf = sG[1 * 512 + r * 32 + uread] + xwv[1][j];
      float zg = sG[2 * 512 + r * 32 + uread] + xwv[2][j];
      float zo = sG[3 * 512 + r * 32 + uread] + xwv[3][j];
      float iv = sigm(zi), fv = sigm(zf), gv = tanh_(zg), ov = sigm(zo);
      float cv = fv * c_st[j] + iv * gv;
      c_st[j] = cv;
      hnew[j] = ov * tanh_(cv);
    }

    if (t < T_C - 1) {
      // ---- h(t+1) coherent packed-u32 stores (wide: 32 lanes/wave active)
      unsigned short* hd = hbuf + (size_t)((t & 1) ^ 1) * (B_C * H_C);
#pragma unroll
      for (int j = 0; j < 2; ++j) {
        float other = __shfl_xor(hnew[j], 1);
        if ((u & 1) == 0) {
          unsigned val = (unsigned)f2bf(hnew[j]) | ((unsigned)f2bf(other) << 16);
          __hip_atomic_store((unsigned*)(hd + (size_t)(brow0 + rbase + j) * H_C + ub + u), val,
                             RLX, AGT);
        }
      }

      // drains every thread's h stores (vmcnt ack = IC visibility), then signal
      __syncthreads();
      if (tid == 0)
        __hip_atomic_store(&cnt[(size_t)(bg * 16 + cg) * 16], (unsigned)(t + 1), RLX, AGT);

      // ---- off-critical-path: xmid (NT) + xw(t+1) prefetch overlap the next poll
#pragma unroll
      for (int j = 0; j < 2; ++j)
        __builtin_nontemporal_store(hnew[j],
            &xmid[((size_t)t * B_C + brow0 + rbase + j) * H_C + ub + u]);
      const _Float16* xp = xb + (size_t)(t + 1) * B_C * G4_C;
#pragma unroll
      for (int g2 = 0; g2 < 4; ++g2)
#pragma unroll
        for (int j = 0; j < 2; ++j)
          xwv[g2][j] = (float)xp[(size_t)j * G4_C + g2 * H_C];
    } else {
#pragma unroll
      for (int j = 0; j < 2; ++j)
        __builtin_nontemporal_store(hnew[j],
            &xmid[((size_t)t * B_C + brow0 + rbase + j) * H_C + ub + u]);
    }
  }
}

// ================= gemm2: xw2 = x_mid @ W2 + b2 (fp32, 1 wave/row, split-K) ========
__global__ void gemm2(const float* __restrict__ X,    // [M1][512]
                      const float* __restrict__ W2T,  // [20][512]
                      const float* __restrict__ b2,   // [20]
                      float* __restrict__ XW2)        // [M1][20]
{
  int wid = (blockIdx.x * blockDim.x + threadIdx.x) >> 6;   // wave id = row
  if (wid >= M1_C) return;
  int l = threadIdx.x & 63;
  const float* xr = X + (size_t)wid * H_C + l * 8;
  f32x4 x0 = *(const f32x4*)(xr);
  f32x4 x1 = *(const f32x4*)(xr + 4);
  float acc[20];
#pragma unroll
  for (int j = 0; j < 20; ++j) {
    const float* wr = W2T + (size_t)j * H_C + l * 8;
    f32x4 w0 = *(const f32x4*)(wr);
    f32x4 w1 = *(const f32x4*)(wr + 4);
    acc[j] = x0[0]*w0[0] + x0[1]*w0[1] + x0[2]*w0[2] + x0[3]*w0[3]
           + x1[0]*w1[0] + x1[1]*w1[1] + x1[2]*w1[2] + x1[3]*w1[3];
  }
#pragma unroll
  for (int off = 32; off >= 1; off >>= 1)
#pragma unroll
    for (int j = 0; j < 20; ++j)
      acc[j] += __shfl_xor(acc[j], off);
  if (l < 5) {
    f32x4 o;
#pragma unroll
    for (int q = 0; q < 4; ++q) o[q] = acc[l * 4 + q] + b2[l * 4 + q];
    *(f32x4*)(XW2 + (size_t)wid * 20 + l * 4) = o;
  }
}

// ================= lstm2: tiny recurrence, fp32 =============
__global__ void lstm2(const float* __restrict__ XW2,  // [M1][20]
                      const float* __restrict__ U2,   // [5][20]
                      float* __restrict__ out)        // [512][11][5][5]
{
  int b = blockIdx.x * blockDim.x + threadIdx.x;
  if (b >= B_C) return;
  float u2[5][20];
#pragma unroll
  for (int k = 0; k < 5; ++k)
#pragma unroll
    for (int j = 0; j < 20; ++j) u2[k][j] = U2[k * 20 + j];
  float h[5] = {0, 0, 0, 0, 0}, c[5] = {0, 0, 0, 0, 0};
  for (int t = 0; t < T_C; ++t) {
    const float* xr = XW2 + ((size_t)t * B_C + b) * 20;
    float z[20];
#pragma unroll
    for (int j = 0; j < 20; ++j) z[j] = xr[j];
#pragma unroll
    for (int k = 0; k < 5; ++k) {
      float hk = h[k];
#pragma unroll
      for (int j = 0; j < 20; ++j) z[j] += hk * u2[k][j];
    }
#pragma unroll
    for (int n = 0; n < 5; ++n) {
      float iv = sigm(z[n]), fv = sigm(z[5 + n]), gv = tanh_(z[10 + n]), ov = sigm(z[15 + n]);
      c[n] = fv * c[n] + iv * gv;
      h[n] = ov * tanh_(c[n]);
    }
    int k1 = t / 5, nn = t - k1 * 5;
    float* op = out + (((size_t)b * 11 + k1) * 5 + nn) * 5;
#pragma unroll
    for (int j = 0; j < 5; ++j) op[j] = h[j];
  }
}

// ================= launch =================
extern "C" void kernel_launch(void* const* d_in, const int* in_sizes, int n_in,
                              void* d_out, int out_size, void* d_ws, size_t ws_size,
                              hipStream_t stream) {
  (void)in_sizes; (void)n_in; (void)out_size; (void)ws_size;
  const float* img = (const float*)d_in[0];
  const float* lbl = (const float*)d_in[1];
  const float* W1  = (const float*)d_in[2];
  const float* U1  = (const float*)d_in[3];
  const float* b1  = (const float*)d_in[4];
  const float* W2  = (const float*)d_in[5];
  const float* U2  = (const float*)d_in[6];
  const float* b2  = (const float*)d_in[7];

  char* ws = (char*)d_ws;
  unsigned short* A    = (unsigned short*)(ws + OFF_A);
  unsigned short* W1T  = (unsigned short*)(ws + OFF_W1T);
  unsigned short* U1T  = (unsigned short*)(ws + OFF_U1T);
  _Float16*       XW1  = (_Float16*)      (ws + OFF_XW1);
  unsigned short* HB   = (unsigned short*)(ws + OFF_H);
  float*          XMID = (float*)         (ws + OFF_XMID);
  float*          XW2  = (float*)         (ws + OFF_XW2);
  float*          W2T  = (float*)         (ws + OFF_W2T);
  unsigned int*   CNT  = (unsigned int*)  (ws + OFF_CNT);

  hipMemsetAsync(CNT, 0, 512 * 64, stream);               // 512 flags, one per 64B line

  {
    constexpr int NTOT = M1_C * (KP_C / 8) + G4_C * KP_C + G4_C * H_C + 20 * H_C;
    pack_all<<<(NTOT + 255) / 256, 256, 0, stream>>>(img, lbl, W1, U1, W2, A, W1T, U1T, W2T);
  }

  gemm1<<<3520, 256, 0, stream>>>(A, W1T, b1, XW1);
  lstm1<<<512, 256, 0, stream>>>(XW1, U1T, HB, XMID, CNT);
  gemm2<<<(M1_C * 64) / 256, 256, 0, stream>>>(XMID, W2T, b2, XW2);
  lstm2<<<8, 64, 0, stream>>>(XW2, U2, (float*)d_out);
}